// Round 4
// baseline (1071.592 us; speedup 1.0000x reference)
//
#include <hip/hip_runtime.h>

typedef unsigned short ushort_t;
typedef unsigned int   uint_t;

typedef ushort_t u16x4  __attribute__((ext_vector_type(4)));
typedef ushort_t u16x8  __attribute__((ext_vector_type(8)));
typedef __bf16   bf16x4 __attribute__((ext_vector_type(4)));
typedef __bf16   bf16x8 __attribute__((ext_vector_type(8)));
typedef float    f32x4  __attribute__((ext_vector_type(4)));

#define DIMSZ 1024

__device__ __forceinline__ ushort_t f2bf(float f) {
  uint_t u = __builtin_bit_cast(uint_t, f);
  u += 0x7fffu + ((u >> 16) & 1u);          // RNE
  return (ushort_t)(u >> 16);
}
__device__ __forceinline__ float bf2f(ushort_t h) {
  uint_t u = ((uint_t)h) << 16;
  return __builtin_bit_cast(float, u);
}
__device__ __forceinline__ void lds_load16(const void* g, void* l) {
  __builtin_amdgcn_global_load_lds((const __attribute__((address_space(1))) void*)g,
                                   (__attribute__((address_space(3))) void*)l, 16, 0, 0);
}
#define SCHED0() __builtin_amdgcn_sched_barrier(0)
#define WBAR() do { SCHED0(); __builtin_amdgcn_s_barrier(); SCHED0(); } while (0)

// ---------- tiled weight transpose + bf16: dst[n*1024+k] = src[k*ld + n] ----------
__global__ __launch_bounds__(256) void wtrans(const float* __restrict__ src, int ld,
                                              ushort_t* __restrict__ dst) {
  __shared__ ushort_t tile[32][33];
  const int bx = blockIdx.x, by = blockIdx.y;
  const int tx = threadIdx.x & 31, ty = threadIdx.x >> 5;
#pragma unroll
  for (int i = 0; i < 32; i += 8)
    tile[ty + i][tx] = f2bf(src[(size_t)(by * 32 + ty + i) * ld + bx * 32 + tx]);
  __syncthreads();
#pragma unroll
  for (int i = 0; i < 32; i += 8)
    dst[(size_t)(bx * 32 + ty + i) * 1024 + by * 32 + tx] = tile[tx][ty + i];
}

// ---------- attention-lite: head dots + softmax -> attn[B,16] f32 ----------
__global__ __launch_bounds__(256) void attn_lite(const ushort_t* __restrict__ qb,
                                                 const ushort_t* __restrict__ kvb,
                                                 float* __restrict__ attn) {
  const int idx = blockIdx.x * 256 + threadIdx.x;
  const int row = idx >> 4, h = idx & 15;
  const ushort_t* qp = qb + (size_t)row * 1024 + h * 64;
  const ushort_t* kp = kvb + (size_t)row * 2048 + h * 64;
  float s = 0.f;
#pragma unroll
  for (int i = 0; i < 64; i += 8) {
    u16x8 q8 = *(const u16x8*)(qp + i);
    u16x8 k8 = *(const u16x8*)(kp + i);
#pragma unroll
    for (int j = 0; j < 8; ++j) s += bf2f(q8[j]) * bf2f(k8[j]);
  }
  s *= 0.015625f;  // scale*scale (faithful double-scale)
  float m = s;
#pragma unroll
  for (int off = 8; off >= 1; off >>= 1) m = fmaxf(m, __shfl_xor(m, off, 16));
  float e = expf(s - m);
  float sum = e;
#pragma unroll
  for (int off = 8; off >= 1; off >>= 1) sum += __shfl_xor(sum, off, 16);
  attn[idx] = e / sum;
}

// ---------- 256x256x(BK=64) 8-wave 8-phase GEMM with fused A transform ----------
// AMODE 0: A = fp32 [M,lda], converted to bf16 in reg-staging.
// AMODE 1: A = bf16 v rows ([M,lda], pre-offset to v) scaled by attn[row][tile].
// B via global_load_lds from pre-swizzled bf16 [N][1024].
// LDS: buf c: A at c*16384 (flat [256][64], XOR swizzle colbyte^=(row&7)<<4),
//      B at 32768 + c*16384 (same swizzle, pre-applied at source).
template <int AMODE, int OUTF32>
__global__ __launch_bounds__(512, 2) void gemm8(const void* __restrict__ Aq,
                                                const float* __restrict__ attnp,
                                                const ushort_t* __restrict__ Bt,
                                                void* __restrict__ Cv,
                                                const float* __restrict__ bias,
                                                int lda, int ldc, int ncol_lg2) {
  __shared__ ushort_t lds[65536];
  const int t = threadIdx.x;
  const int nb8 = gridDim.x >> 3;                      // XCD-aware bijective swizzle
  const int nbid = (blockIdx.x & 7) * nb8 + (blockIdx.x >> 3);
  const int n0 = (nbid & ((1 << ncol_lg2) - 1)) * 256;
  const int m0 = (nbid >> ncol_lg2) * 256;
  const int w = t >> 6, lane = t & 63;
  const int wm = w >> 2, wn = w & 3;
  const int lr = lane & 15, lk = lane >> 4;
  const int w512 = w * 512;

  // B staging source (pre-swizzled global column)
  const int srow = w * 8 + (lane >> 3);
  const int scsw = ((lane & 7) * 16) ^ ((srow & 7) << 4);
  const ushort_t* bS = Bt + (size_t)(n0 + srow) * DIMSZ + (scsw >> 1);

  // A reg-staging geometry: thread covers rows {sr_base + 4s}, cols [sc4, sc4+4)
  const int sr_base = w * 32 + lk;                     // + s*4, 0..255
  const int sc4 = lr * 4;
  const float*    aF  = (const float*)Aq + (size_t)(m0 + sr_base) * lda + sc4;
  const ushort_t* aH  = (const ushort_t*)Aq + (size_t)(m0 + sr_base) * lda + sc4;
  const float*    atS = attnp ? (attnp + (size_t)(m0 + sr_base) * 16) : (const float*)Aq;

  // fragment ds_read offsets (elems), swizzled
  const int cbe0 = ((lk * 16) ^ ((lr & 7) << 4)) >> 1;
  const int cbe1 = ((64 + lk * 16) ^ ((lr & 7) << 4)) >> 1;
  const int aRB = lr * 64;
  const int bRB = 32768 + (wn * 64 + lr) * 64;

  f32x4 acc[8][4];
  const f32x4 zf = {0.f, 0.f, 0.f, 0.f};
#pragma unroll
  for (int i = 0; i < 8; ++i)
#pragma unroll
    for (int j = 0; j < 4; ++j) acc[i][j] = zf;
  bf16x8 a[4][2], b0[2][2], b1[2][2];
  f32x4 areg[8];
  u16x4 vreg[8];
  float sreg[8];

#define LOADA(tt) do {                                                    \
    if constexpr (AMODE == 0) {                                           \
      _Pragma("unroll") for (int s = 0; s < 8; ++s)                       \
        areg[s] = *(const f32x4*)(aF + (size_t)s * 4 * lda + (tt) * 64);  \
    } else {                                                              \
      _Pragma("unroll") for (int s = 0; s < 8; ++s) {                     \
        vreg[s] = *(const u16x4*)(aH + (size_t)s * 4 * lda + (tt) * 64);  \
        sreg[s] = atS[s * 64 + (tt)]; } } } while (0)
#define CVTW(bc) do {                                                     \
    _Pragma("unroll") for (int s = 0; s < 8; ++s) {                       \
      const int r_ = sr_base + s * 4;                                     \
      char* dp_ = (char*)lds + (size_t)((bc) * 32768 + r_ * 128 +         \
                  ((sc4 * 2) ^ ((r_ & 7) << 4)));                         \
      bf16x4 o_;                                                          \
      if constexpr (AMODE == 0) {                                         \
        _Pragma("unroll") for (int j = 0; j < 4; ++j) o_[j] = (__bf16)areg[s][j]; \
      } else {                                                            \
        _Pragma("unroll") for (int j = 0; j < 4; ++j)                     \
          o_[j] = (__bf16)(bf2f(vreg[s][j]) * sreg[s]); }                 \
      *(bf16x4*)dp_ = o_; } } while (0)
#define STAGE_B(cc, hh, tt) do {                                          \
    const ushort_t* s_ = bS + (size_t)(hh) * (128 * DIMSZ) + (tt) * 64;   \
    ushort_t* d_ = lds + 32768 + (cc) * 16384 + (hh) * 8192 + w512;       \
    lds_load16(s_, d_);                                                   \
    lds_load16(s_ + 64 * DIMSZ, d_ + 4096); } while (0)
#define LDA(cc, mq) do {                                                  \
    const ushort_t* Lp = lds + (cc) * 16384 + (wm * 2 + (mq)) * 4096 + aRB; \
    _Pragma("unroll") for (int j = 0; j < 4; ++j) {                       \
      a[j][0] = *(const bf16x8*)(Lp + j * 1024 + cbe0);                   \
      a[j][1] = *(const bf16x8*)(Lp + j * 1024 + cbe1); } } while (0)
#define LDB(cc, dst, nq) do {                                             \
    const ushort_t* Lp = lds + (cc) * 16384 + bRB + (nq) * 2048;          \
    _Pragma("unroll") for (int ni = 0; ni < 2; ++ni) {                    \
      dst[ni][0] = *(const bf16x8*)(Lp + ni * 1024 + cbe0);               \
      dst[ni][1] = *(const bf16x8*)(Lp + ni * 1024 + cbe1); } } while (0)
#define MMQ(mb, B, nb) do {                                               \
    _Pragma("unroll") for (int j = 0; j < 4; ++j)                         \
    _Pragma("unroll") for (int ni = 0; ni < 2; ++ni)                      \
    _Pragma("unroll") for (int ks = 0; ks < 2; ++ks)                      \
      acc[(mb) + j][(nb) + ni] = __builtin_amdgcn_mfma_f32_16x16x32_bf16( \
          a[j][ks], B[ni][ks], acc[(mb) + j][(nb) + ni], 0, 0, 0); } while (0)
#define TILE(IA, SB, VM, CV, tv, c) do {                                  \
    LDA(c, 0); LDB(c, b0, 0);                                             \
    if (IA) LOADA((tv) + 1);                                              \
    WBAR();                                                               \
    __builtin_amdgcn_s_setprio(1); MMQ(0, b0, 0); __builtin_amdgcn_s_setprio(0); \
    WBAR();                                                               \
    LDB(c, b1, 1);                                                        \
    WBAR();                                                               \
    __builtin_amdgcn_s_setprio(1); MMQ(0, b1, 2); __builtin_amdgcn_s_setprio(0); \
    WBAR();                                                               \
    LDA(c, 1);                                                            \
    if (SB) STAGE_B(c, 0, (tv) + 2);                                      \
    WBAR();                                                               \
    __builtin_amdgcn_s_setprio(1); MMQ(4, b1, 2); __builtin_amdgcn_s_setprio(0); \
    WBAR();                                                               \
    if (SB) STAGE_B(c, 1, (tv) + 2);                                      \
    if ((VM) == 4)      asm volatile("s_waitcnt vmcnt(4)" ::: "memory");  \
    else if ((VM) == 0) asm volatile("s_waitcnt vmcnt(0)" ::: "memory");  \
    if (CV) { CVTW((c) ^ 1);                                              \
      asm volatile("s_waitcnt lgkmcnt(0)" ::: "memory"); }                \
    WBAR();                                                               \
    __builtin_amdgcn_s_setprio(1); MMQ(4, b0, 0); __builtin_amdgcn_s_setprio(0); \
    WBAR();                                                               \
  } while (0)

  // ---- prologue: A(0)+B(0), convert A(0); A(1)+B(1) left in flight ----
  LOADA(0);
  STAGE_B(0, 0, 0); STAGE_B(0, 1, 0);
  asm volatile("s_waitcnt vmcnt(4)" ::: "memory");     // A(0) regs ready
  CVTW(0);
  LOADA(1);
  STAGE_B(1, 0, 1); STAGE_B(1, 1, 1);
  if constexpr (AMODE == 0) asm volatile("s_waitcnt vmcnt(12)" ::: "memory"); // B(0) landed
  else                      asm volatile("s_waitcnt vmcnt(20)" ::: "memory");
  asm volatile("s_waitcnt lgkmcnt(0)" ::: "memory");   // A(0) ds_writes done
  WBAR();

  TILE(0, 1, 4, 1, 0, 0);                              // tile 0
  for (int tt2 = 0; tt2 < 6; ++tt2) {
    const int tv = tt2 * 2 + 1;
    TILE(1, 1, 4, 1, tv, 1);                           // tiles 1,3,..,11
    TILE(1, 1, 4, 1, tv + 1, 0);                       // tiles 2,4,..,12
  }
  TILE(1, 1, 4, 1, 13, 1);
  TILE(1, 0, 0, 1, 14, 0);
  TILE(0, 0, -1, 0, 15, 1);

#undef TILE
#undef MMQ
#undef LDB
#undef LDA
#undef STAGE_B
#undef CVTW
#undef LOADA

  if (!OUTF32) {
    // bf16 epilogue via per-wave LDS bounce for 128B-coalesced stores
    ushort_t* Cp = (ushort_t*)Cv;
    ushort_t* ep = lds + w * 8192;
#pragma unroll
    for (int mq = 0; mq < 2; ++mq)
#pragma unroll
      for (int j = 0; j < 4; ++j)
#pragma unroll
        for (int ni = 0; ni < 4; ++ni)
#pragma unroll
          for (int r = 0; r < 4; ++r) {
            const int row = mq * 64 + j * 16 + lk * 4 + r;
            const int ce = ((ni * 16 + lr) * 2) ^ ((row & 7) << 4);
            ep[row * 64 + (ce >> 1)] = f2bf(acc[mq * 4 + j][ni][r]);
          }
#pragma unroll
    for (int rr = 0; rr < 16; ++rr) {
      const int row = rr * 8 + (lane >> 3);
      const int ce = ((lane & 7) * 16) ^ ((lane >> 3) << 4);
      u16x8 vv = *(const u16x8*)(ep + row * 64 + (ce >> 1));
      *(u16x8*)(Cp + (size_t)(m0 + wm * 128 + row) * ldc + n0 + wn * 64 + (lane & 7) * 8) = vv;
    }
  } else {
    float* Op = (float*)Cv;
    float bb[4];
#pragma unroll
    for (int ni = 0; ni < 4; ++ni) bb[ni] = bias[n0 + wn * 64 + ni * 16 + lr];
#pragma unroll
    for (int mq = 0; mq < 2; ++mq)
#pragma unroll
      for (int j = 0; j < 4; ++j)
#pragma unroll
        for (int ni = 0; ni < 4; ++ni)
#pragma unroll
          for (int r = 0; r < 4; ++r)
            Op[(size_t)(m0 + wm * 128 + mq * 64 + j * 16 + lk * 4 + r) * 1024 +
               n0 + wn * 64 + ni * 16 + lr] = acc[mq * 4 + j][ni][r] + bb[ni];
  }
}

extern "C" void kernel_launch(void* const* d_in, const int* in_sizes, int n_in,
                              void* d_out, int out_size, void* d_ws, size_t ws_size,
                              hipStream_t stream) {
  const float* x   = (const float*)d_in[0];
  const float* y   = (const float*)d_in[1];
  const float* Wq  = (const float*)d_in[3];
  const float* Wkv = (const float*)d_in[4];
  const float* Wp  = (const float*)d_in[5];
  const float* bp  = (const float*)d_in[6];
  (void)in_sizes; (void)n_in; (void)out_size; (void)ws_size;

  char* ws = (char*)d_ws;
  ushort_t* Wqt   = (ushort_t*)(ws);                    //   2 MiB [1024][1024]
  ushort_t* Wkvt  = (ushort_t*)(ws + (2ull   << 20));   //   4 MiB [2048][1024] (k|v)
  ushort_t* Wpt   = (ushort_t*)(ws + (6ull   << 20));   //   2 MiB [1024][1024]
  float*    attnb = (float*)   (ws + (8ull   << 20));   //   4 MiB [65536][16]
  ushort_t* qb    = (ushort_t*)(ws + (12ull  << 20));   // 128 MiB q bf16
  ushort_t* kvb   = (ushort_t*)(ws + (140ull << 20));   // 256 MiB kv bf16 (k|v)

  wtrans<<<dim3(32, 32), 256, 0, stream>>>(Wq, 1024, Wqt);
  wtrans<<<dim3(64, 32), 256, 0, stream>>>(Wkv, 2048, Wkvt);
  wtrans<<<dim3(32, 32), 256, 0, stream>>>(Wp, 1024, Wpt);

  // kv = cvt(y) @ Wkv   (A: fp32 direct, fused convert)
  gemm8<0, 0><<<2048, 512, 0, stream>>>((const void*)y, nullptr, Wkvt, kvb, nullptr,
                                        1024, 2048, 3);
  // q = cvt(x) @ Wq
  gemm8<0, 0><<<1024, 512, 0, stream>>>((const void*)x, nullptr, Wqt, qb, nullptr,
                                        1024, 1024, 2);
  // attn[B,16]
  attn_lite<<<4096, 256, 0, stream>>>(qb, kvb, attnb);
  // out = (attn .* v) @ Wproj + bproj   (A: v bf16 scaled in staging)
  gemm8<1, 1><<<1024, 512, 0, stream>>>((const void*)(kvb + 1024), attnb, Wpt, d_out, bp,
                                        2048, 1024, 2);
}

// Round 5
// 813.592 us; speedup vs baseline: 1.3171x; 1.3171x over previous
//
#include <hip/hip_runtime.h>

typedef unsigned short ushort_t;
typedef unsigned int   uint_t;

typedef ushort_t u16x8  __attribute__((ext_vector_type(8)));
typedef __bf16   bf16x8 __attribute__((ext_vector_type(8)));
typedef float    f32x4  __attribute__((ext_vector_type(4)));

#define DIMSZ 1024

__device__ __forceinline__ ushort_t f2bf(float f) {
  uint_t u = __builtin_bit_cast(uint_t, f);
  u += 0x7fffu + ((u >> 16) & 1u);          // RNE
  return (ushort_t)(u >> 16);
}
__device__ __forceinline__ float bf2f(ushort_t h) {
  uint_t u = ((uint_t)h) << 16;
  return __builtin_bit_cast(float, u);
}
__device__ __forceinline__ void lds_load16(const void* g, void* l) {
  __builtin_amdgcn_global_load_lds((const __attribute__((address_space(1))) void*)g,
                                   (__attribute__((address_space(3))) void*)l, 16, 0, 0);
}
#define SCHED0() __builtin_amdgcn_sched_barrier(0)
#define WBAR() do { SCHED0(); __builtin_amdgcn_s_barrier(); SCHED0(); } while (0)

// ---------- tiled weight transpose + bf16: dst[n*1024+k] = src[k*ld + n] ----------
__global__ __launch_bounds__(256) void wtrans(const float* __restrict__ src, int ld,
                                              ushort_t* __restrict__ dst) {
  __shared__ ushort_t tile[32][33];
  const int bx = blockIdx.x, by = blockIdx.y;
  const int tx = threadIdx.x & 31, ty = threadIdx.x >> 5;
#pragma unroll
  for (int i = 0; i < 32; i += 8)
    tile[ty + i][tx] = f2bf(src[(size_t)(by * 32 + ty + i) * ld + bx * 32 + tx]);
  __syncthreads();
#pragma unroll
  for (int i = 0; i < 32; i += 8)
    dst[(size_t)(bx * 32 + ty + i) * 1024 + by * 32 + tx] = tile[tx][ty + i];
}

// ---------- fp32 -> bf16 convert (64M elements), grid-stride ----------
__global__ __launch_bounds__(256) void cvt_bf16(const float* __restrict__ s,
                                                ushort_t* __restrict__ d) {
  const size_t n8 = (size_t)65536 * 1024 / 8;
  const size_t stride = (size_t)gridDim.x * 256;
  for (size_t i = (size_t)blockIdx.x * 256 + threadIdx.x; i < n8; i += stride) {
    f32x4 f0 = *(const f32x4*)(s + i * 8);
    f32x4 f1 = *(const f32x4*)(s + i * 8 + 4);
    u16x8 o;
#pragma unroll
    for (int j = 0; j < 4; ++j) { o[j] = f2bf(f0[j]); o[4 + j] = f2bf(f1[j]); }
    *(u16x8*)(d + i * 8) = o;
  }
}

// ---------- softmax over 16 heads, in place on dots[B,16] ----------
__global__ __launch_bounds__(256) void softmax16(float* __restrict__ d) {
  const int row = blockIdx.x * 256 + threadIdx.x;
  f32x4 v[4];
#pragma unroll
  for (int i = 0; i < 4; ++i) v[i] = *(const f32x4*)(d + (size_t)row * 16 + i * 4);
  float m = v[0][0];
#pragma unroll
  for (int i = 0; i < 4; ++i)
#pragma unroll
    for (int j = 0; j < 4; ++j) m = fmaxf(m, v[i][j]);
  float sum = 0.f;
#pragma unroll
  for (int i = 0; i < 4; ++i)
#pragma unroll
    for (int j = 0; j < 4; ++j) { v[i][j] = expf(v[i][j] - m); sum += v[i][j]; }
  const float r = 1.f / sum;
#pragma unroll
  for (int i = 0; i < 4; ++i) {
#pragma unroll
    for (int j = 0; j < 4; ++j) v[i][j] *= r;
    *(f32x4*)(d + (size_t)row * 16 + i * 4) = v[i];
  }
}

// ---------- ab = attn .* v  (bf16) ----------
__global__ __launch_bounds__(256) void abk(const ushort_t* __restrict__ kvb,
                                           const float* __restrict__ at,
                                           ushort_t* __restrict__ ab) {
  const size_t stride = (size_t)gridDim.x * 256;
  for (size_t g = (size_t)blockIdx.x * 256 + threadIdx.x; g < (size_t)8388608; g += stride) {
    const int row = (int)(g >> 7), c8 = (int)(g & 127);
    const float sc = at[(size_t)row * 16 + (c8 >> 3)];
    u16x8 v8 = *(const u16x8*)(kvb + (size_t)row * 2048 + 1024 + c8 * 8);
    u16x8 o;
#pragma unroll
    for (int j = 0; j < 8; ++j) o[j] = f2bf(bf2f(v8[j]) * sc);
    *(u16x8*)(ab + (size_t)row * 1024 + c8 * 8) = o;
  }
}

// ---------- 256x256x(BK=64) 8-wave 8-phase bf16 GEMM: C = A[M,1024] @ Bt[N,1024]^T ----------
// Round-3 proven core. EPI 0: C bf16 (ldc). EPI 1: C f32 + bias (ldc=1024).
// EPI 2: no C write; epilogue computes dots[row,head] = 0.015625 * sum(acc * k)
//        where head = wave's 64-col span; k read from kvp [M,2048] (k half).
template <int EPI>
__global__ __launch_bounds__(512, 2) void gemm8(const ushort_t* __restrict__ A,
                                                const ushort_t* __restrict__ Bt,
                                                void* __restrict__ Cv,
                                                const float* __restrict__ bias,
                                                const ushort_t* __restrict__ kvp,
                                                float* __restrict__ dots,
                                                int ldc, int ncol_lg2) {
  __shared__ ushort_t lds[65536];
  const int t = threadIdx.x;
  const int nb8 = gridDim.x >> 3;                       // XCD-aware bijective swizzle
  const int nbid = (blockIdx.x & 7) * nb8 + (blockIdx.x >> 3);
  const int n0 = (nbid & ((1 << ncol_lg2) - 1)) * 256;
  const int m0 = (nbid >> ncol_lg2) * 256;
  const int w = t >> 6, lane = t & 63;
  const int wm = w >> 2, wn = w & 3;
  const int lr = lane & 15, lk = lane >> 4;
  const int w512 = w * 512;

  // staging source (per-thread, swizzle pre-applied to global column)
  const int srow = w * 8 + (lane >> 3);                 // 0..63 within a 64-row block
  const int scsw = ((lane & 7) * 16) ^ ((srow & 7) << 4);
  const ushort_t* aS = A + (size_t)(m0 + srow) * DIMSZ + (scsw >> 1);
  const ushort_t* bS = Bt + (size_t)(n0 + srow) * DIMSZ + (scsw >> 1);

  // fragment ds_read offsets (elems), swizzled
  const int cbe0 = (((lk * 16)) ^ ((lr & 7) << 4)) >> 1;         // ks=0
  const int cbe1 = ((64 + lk * 16) ^ ((lr & 7) << 4)) >> 1;      // ks=1
  const int aRB = lr * 64;
  const int bRB = 32768 + (wn * 64 + lr) * 64;

  f32x4 acc[8][4];
  const f32x4 zf = {0.f, 0.f, 0.f, 0.f};
#pragma unroll
  for (int i = 0; i < 8; ++i)
#pragma unroll
    for (int j = 0; j < 4; ++j) acc[i][j] = zf;
  bf16x8 a[4][2], b0[2][2], b1[2][2];

  // A half h (=mq) -> blocks {h, h+2}; B half h -> rows [h*128, h*128+128)
#define STAGE_A(cc, hh, tt) do {                                          \
    const ushort_t* s_ = aS + (size_t)(hh) * 65536 + (tt) * 64;           \
    ushort_t* d_ = lds + (cc) * 16384 + (hh) * 4096 + w512;               \
    lds_load16(s_, d_);                                                   \
    lds_load16(s_ + 131072, d_ + 8192); } while (0)
#define STAGE_B(cc, hh, tt) do {                                          \
    const ushort_t* s_ = bS + (size_t)(hh) * 131072 + (tt) * 64;          \
    ushort_t* d_ = lds + 32768 + (cc) * 16384 + (hh) * 8192 + w512;       \
    lds_load16(s_, d_);                                                   \
    lds_load16(s_ + 65536, d_ + 4096); } while (0)
#define LDA(cc, mq) do {                                                  \
    const ushort_t* Lp = lds + (cc) * 16384 + (wm * 2 + (mq)) * 4096 + aRB; \
    _Pragma("unroll") for (int j = 0; j < 4; ++j) {                       \
      a[j][0] = *(const bf16x8*)(Lp + j * 1024 + cbe0);                   \
      a[j][1] = *(const bf16x8*)(Lp + j * 1024 + cbe1); } } while (0)
#define LDB(cc, dst, nq) do {                                             \
    const ushort_t* Lp = lds + (cc) * 16384 + bRB + (nq) * 2048;          \
    _Pragma("unroll") for (int ni = 0; ni < 2; ++ni) {                    \
      dst[ni][0] = *(const bf16x8*)(Lp + ni * 1024 + cbe0);               \
      dst[ni][1] = *(const bf16x8*)(Lp + ni * 1024 + cbe1); } } while (0)
#define MMQ(mb, B, nb) do {                                               \
    _Pragma("unroll") for (int j = 0; j < 4; ++j)                         \
    _Pragma("unroll") for (int ni = 0; ni < 2; ++ni)                      \
    _Pragma("unroll") for (int ks = 0; ks < 2; ++ks)                      \
      acc[(mb) + j][(nb) + ni] = __builtin_amdgcn_mfma_f32_16x16x32_bf16( \
          a[j][ks], B[ni][ks], acc[(mb) + j][(nb) + ni], 0, 0, 0); } while (0)
#define TILE(S1, S2, VM, tv, c, nxt) do {                                 \
    LDA(c, 0); LDB(c, b0, 0);                                             \
    if (S1) STAGE_A(nxt, 1, (tv) + 1);                                    \
    WBAR();                                                               \
    __builtin_amdgcn_s_setprio(1); MMQ(0, b0, 0); __builtin_amdgcn_s_setprio(0); \
    WBAR();                                                               \
    LDB(c, b1, 1);                                                        \
    if (S2) STAGE_A(c, 0, (tv) + 2);                                      \
    WBAR();                                                               \
    __builtin_amdgcn_s_setprio(1); MMQ(0, b1, 2); __builtin_amdgcn_s_setprio(0); \
    WBAR();                                                               \
    LDA(c, 1);                                                            \
    if (S2) STAGE_B(c, 0, (tv) + 2);                                      \
    WBAR();                                                               \
    __builtin_amdgcn_s_setprio(1); MMQ(4, b1, 2); __builtin_amdgcn_s_setprio(0); \
    WBAR();                                                               \
    if (S2) STAGE_B(c, 1, (tv) + 2);                                      \
    if ((VM) == 6) { asm volatile("s_waitcnt vmcnt(6)" ::: "memory"); }   \
    else if ((VM) == 0) { asm volatile("s_waitcnt vmcnt(0)" ::: "memory"); } \
    WBAR();                                                               \
    __builtin_amdgcn_s_setprio(1); MMQ(4, b0, 0); __builtin_amdgcn_s_setprio(0); \
    WBAR();                                                               \
  } while (0)

  // prologue: tile0 {Ah0,Ah1,Bh0,Bh1}, tile1 {Ah0,Bh0,Bh1}; leave tile1's 3 halves in flight
  STAGE_A(0, 0, 0); STAGE_A(0, 1, 0); STAGE_B(0, 0, 0); STAGE_B(0, 1, 0);
  STAGE_A(1, 0, 1); STAGE_B(1, 0, 1); STAGE_B(1, 1, 1);
  asm volatile("s_waitcnt vmcnt(6)" ::: "memory");
  WBAR();

  for (int tt = 0; tt < 7; ++tt) {
    const int t0 = tt * 2;
    TILE(1, 1, 6, t0, 0, 1);
    TILE(1, 1, 6, t0 + 1, 1, 0);
  }
  TILE(1, 0, 0, 14, 0, 1);
  TILE(0, 0, -1, 15, 1, 0);

#undef TILE
#undef MMQ
#undef LDB
#undef LDA
#undef STAGE_B
#undef STAGE_A

  if constexpr (EPI == 0) {
    // bf16 epilogue: bounce through per-wave 16KB LDS slice for 128B-coalesced stores
    ushort_t* Cp = (ushort_t*)Cv;
    ushort_t* ep = lds + w * 8192;
#pragma unroll
    for (int mq = 0; mq < 2; ++mq)
#pragma unroll
      for (int j = 0; j < 4; ++j)
#pragma unroll
        for (int ni = 0; ni < 4; ++ni)
#pragma unroll
          for (int r = 0; r < 4; ++r) {
            const int row = mq * 64 + j * 16 + lk * 4 + r;
            const int ce = ((ni * 16 + lr) * 2) ^ ((row & 7) << 4);
            ep[row * 64 + (ce >> 1)] = f2bf(acc[mq * 4 + j][ni][r]);
          }
#pragma unroll
    for (int rr = 0; rr < 16; ++rr) {
      const int row = rr * 8 + (lane >> 3);
      const int ce = ((lane & 7) * 16) ^ ((lane >> 3) << 4);
      u16x8 vv = *(const u16x8*)(ep + row * 64 + (ce >> 1));
      *(u16x8*)(Cp + (size_t)(m0 + wm * 128 + row) * ldc + n0 + wn * 64 + (lane & 7) * 8) = vv;
    }
  } else if constexpr (EPI == 1) {
    float* Op = (float*)Cv;
    float bb[4];
#pragma unroll
    for (int ni = 0; ni < 4; ++ni) bb[ni] = bias[n0 + wn * 64 + ni * 16 + lr];
#pragma unroll
    for (int mq = 0; mq < 2; ++mq)
#pragma unroll
      for (int j = 0; j < 4; ++j)
#pragma unroll
        for (int ni = 0; ni < 4; ++ni)
#pragma unroll
          for (int r = 0; r < 4; ++r)
            Op[(size_t)(m0 + wm * 128 + mq * 64 + j * 16 + lk * 4 + r) * 1024 +
               n0 + wn * 64 + ni * 16 + lr] = acc[mq * 4 + j][ni][r] + bb[ni];
  } else {
    // dots epilogue: this wave's 64 cols = one head h; stage k[128 rows][64] to LDS,
    // dot with acc along cols, width-16 shfl reduce, write dots[row, h].
    const int h = (n0 >> 6) + wn;
    ushort_t* kw = lds + w * 8192;       // 16 KiB per-wave slice (whole LDS free now)
    const int rsub = lane >> 3, c8 = (lane & 7) * 8;
    const ushort_t* kS = kvp + (size_t)(m0 + wm * 128 + rsub) * 2048 + h * 64 + c8;
#pragma unroll
    for (int i = 0; i < 16; ++i)
      lds_load16(kS + (size_t)i * 8 * 2048, kw + i * 512);
    asm volatile("s_waitcnt vmcnt(0)" ::: "memory");
#pragma unroll
    for (int mq = 0; mq < 2; ++mq)
#pragma unroll
      for (int j = 0; j < 4; ++j)
#pragma unroll
        for (int r = 0; r < 4; ++r) {
          const int row = mq * 64 + j * 16 + lk * 4 + r;
          float p = 0.f;
#pragma unroll
          for (int ni = 0; ni < 4; ++ni)
            p += acc[mq * 4 + j][ni][r] * bf2f(kw[row * 64 + ni * 16 + lr]);
#pragma unroll
          for (int off = 1; off < 16; off <<= 1) p += __shfl_xor(p, off, 16);
          if (lr == 0)
            dots[(size_t)(m0 + wm * 128 + row) * 16 + h] = p * 0.015625f;
        }
  }
}

extern "C" void kernel_launch(void* const* d_in, const int* in_sizes, int n_in,
                              void* d_out, int out_size, void* d_ws, size_t ws_size,
                              hipStream_t stream) {
  const float* x   = (const float*)d_in[0];
  const float* y   = (const float*)d_in[1];
  const float* Wq  = (const float*)d_in[3];
  const float* Wkv = (const float*)d_in[4];
  const float* Wp  = (const float*)d_in[5];
  const float* bp  = (const float*)d_in[6];
  (void)in_sizes; (void)n_in; (void)out_size; (void)ws_size;

  char* ws = (char*)d_ws;                               // 396 MiB total
  ushort_t* Wqt   = (ushort_t*)(ws);                    //   2 MiB [1024][1024]
  ushort_t* Wkvt  = (ushort_t*)(ws + (2ull   << 20));   //   4 MiB [2048][1024] (k|v)
  ushort_t* Wpt   = (ushort_t*)(ws + (6ull   << 20));   //   2 MiB [1024][1024]
  float*    dotsb = (float*)   (ws + (8ull   << 20));   //   4 MiB [65536][16] dots->attn
  ushort_t* kvb   = (ushort_t*)(ws + (12ull  << 20));   // 256 MiB [65536][2048] kv
  ushort_t* actb  = (ushort_t*)(ws + (268ull << 20));   // 128 MiB yb -> xb -> ab

  wtrans<<<dim3(32, 32), 256, 0, stream>>>(Wq, 1024, Wqt);
  wtrans<<<dim3(64, 32), 256, 0, stream>>>(Wkv, 2048, Wkvt);
  wtrans<<<dim3(32, 32), 256, 0, stream>>>(Wp, 1024, Wpt);

  // kv = cvt(y) @ Wkv
  cvt_bf16<<<4096, 256, 0, stream>>>(y, actb);
  gemm8<0><<<2048, 512, 0, stream>>>(actb, Wkvt, kvb, nullptr, nullptr, nullptr, 2048, 3);

  // dots = per-head <q, k>: q-GEMM with fused dots epilogue (q never materialized)
  cvt_bf16<<<4096, 256, 0, stream>>>(x, actb);
  gemm8<2><<<1024, 512, 0, stream>>>(actb, Wqt, nullptr, nullptr, kvb, dotsb, 1024, 2);

  // softmax over heads, in place
  softmax16<<<256, 256, 0, stream>>>(dotsb);

  // ab = attn .* v  (reuse actb)
  abk<<<2048, 256, 0, stream>>>(kvb, dotsb, actb);

  // out = ab @ Wproj + bproj (f32)
  gemm8<1><<<1024, 512, 0, stream>>>(actb, Wpt, d_out, bp, nullptr, nullptr, 1024, 2);
}